// Round 6
// baseline (632.351 us; speedup 1.0000x reference)
//
#include <hip/hip_runtime.h>
#include <math.h>

#define LN_EPS 1e-5f

typedef __attribute__((ext_vector_type(8))) short bf16x8;
typedef __attribute__((ext_vector_type(4))) float f32x4;
typedef __attribute__((ext_vector_type(16))) float f32x16;

// async global->LDS, 16B per lane; LDS dest is wave-uniform base + lane*16
#define GLDS16(g, l) __builtin_amdgcn_global_load_lds( \
    (const __attribute__((address_space(1))) unsigned int*)(g), \
    (__attribute__((address_space(3))) unsigned int*)(l), 16, 0, 0)

__device__ __forceinline__ float b2f(unsigned short h) { return __uint_as_float(((unsigned)h) << 16); }
__device__ __forceinline__ unsigned short f2b(float f) {
  unsigned u = __float_as_uint(f);
  unsigned r = (u + 0x7fffu + ((u >> 16) & 1u)) >> 16;
  return (unsigned short)r;
}
__device__ __forceinline__ float ld(const float* p) { return *p; }
__device__ __forceinline__ float ld(const unsigned short* p) { return b2f(*p); }
__device__ __forceinline__ void st(float* p, float v) { *p = v; }
__device__ __forceinline__ void st(unsigned short* p, float v) { *p = f2b(v); }

// ---------- block reduction helpers (256 threads, 4 waves) ----------
__device__ __forceinline__ float bred_sum(float v, float* red) {
  for (int o = 32; o; o >>= 1) v += __shfl_down(v, o, 64);
  int wid = threadIdx.x >> 6;
  __syncthreads();
  if ((threadIdx.x & 63) == 0) red[wid] = v;
  __syncthreads();
  return red[0] + red[1] + red[2] + red[3];
}

// ---------- folded BN ----------
__global__ void fold_bn(const float* b1, const float* g1, const float* be1,
                        const float* m1, const float* v1,
                        const float* b2, const float* g2, const float* be2,
                        const float* m2, const float* v2,
                        float* s1, float* f1, float* s2, float* f2) {
  int t = blockIdx.x * 256 + threadIdx.x;
  if (t < 1024) { float s = g1[t] * rsqrtf(v1[t] + LN_EPS); s1[t] = s; f1[t] = (b1[t] - m1[t]) * s + be1[t]; }
  if (t < 512)  { float s = g2[t] * rsqrtf(v2[t] + LN_EPS); s2[t] = s; f2[t] = (b2[t] - m2[t]) * s + be2[t]; }
}

// ---------- f32 -> bf16 elementwise ----------
__global__ void cvt_bf16(const float* __restrict__ s, unsigned short* __restrict__ d, int n) {
  int i = blockIdx.x * 256 + threadIdx.x;
  if (i < n) d[i] = f2b(s[i]);
}

// ---------- build concatenated QK weights/bias, q-side prescaled by 512^-0.5 ----------
__global__ void prep_qk(const float* __restrict__ qw, const float* __restrict__ qb,
                        const float* __restrict__ kw, const float* __restrict__ kb,
                        unsigned short* __restrict__ qkw, float* __restrict__ qkbias) {
  const float scl = 0.044194173824159216f;
  int idx = blockIdx.x * 256 + threadIdx.x;   // over 3*1024*512
  if (idx < 1572864) {
    int j = idx >> 19; int r = idx & 524287; int n = r >> 9; int k = r & 511;
    float v = (n < 512) ? qw[j * 262144 + n * 512 + k] * scl
                        : kw[j * 262144 + (n - 512) * 512 + k];
    qkw[idx] = f2b(v);
  }
  if (idx < 3072) {
    int j = idx >> 10, n = idx & 1023;
    qkbias[idx] = (n < 512) ? qb[j * 512 + n] * scl : kb[j * 512 + n - 512];
  }
}

// ---------- 32x32 tiled transpose, typed: src[R][Cc] -> dst[Cc][R] ----------
template<typename TS, typename TD>
__global__ __launch_bounds__(256) void transpose_t(const TS* __restrict__ src,
    TD* __restrict__ dst, int R, int Cc, long sS, long sD) {
  __shared__ float t[32][33];
  src += (long)blockIdx.z * sS; dst += (long)blockIdx.z * sD;
  int c0 = blockIdx.x * 32, r0 = blockIdx.y * 32;
  int tx = threadIdx.x & 31, ty = threadIdx.x >> 5;
#pragma unroll
  for (int rr = 0; rr < 32; rr += 8) t[ty + rr][tx] = ld(&src[(long)(r0 + ty + rr) * Cc + c0 + tx]);
  __syncthreads();
#pragma unroll
  for (int rr = 0; rr < 32; rr += 8) st(&dst[(long)(c0 + ty + rr) * R + r0 + tx], t[tx][ty + rr]);
}

// ---------- row softmax f32 -> bf16, row length PER*256 ----------
template<int PER>
__global__ __launch_bounds__(256) void softmax_k(const float* __restrict__ x,
    unsigned short* __restrict__ y, long bstr) {
  __shared__ float red[4];
  const int L = PER * 256;
  int b = blockIdx.y, r = blockIdx.x, tid = threadIdx.x;
  const float* p = x + (long)b * bstr + (long)r * L;
  unsigned short* o = y + (long)b * bstr + (long)r * L;
  float vals[PER];
  float mx = -1e30f;
#pragma unroll
  for (int t = 0; t < PER; t++) { float v = p[tid + (t << 8)]; vals[t] = v; mx = fmaxf(mx, v); }
  for (int ofs = 32; ofs; ofs >>= 1) mx = fmaxf(mx, __shfl_down(mx, ofs, 64));
  int wid = tid >> 6;
  if ((tid & 63) == 0) red[wid] = mx;
  __syncthreads();
  mx = fmaxf(fmaxf(red[0], red[1]), fmaxf(red[2], red[3]));
  float sm = 0.f;
#pragma unroll
  for (int t = 0; t < PER; t++) { float e = __expf(vals[t] - mx); vals[t] = e; sm += e; }
  sm = bred_sum(sm, red);
  float inv = 1.f / sm;
#pragma unroll
  for (int t = 0; t < PER; t++) o[tid + (t << 8)] = f2b(vals[t] * inv);
}

// ---------- bf16 MFMA GEMM: C[m,n] = sum_k A[m,k]*B[n,k], both k-contig ----------
// 128x128 tile, 4 waves of 64x64, BK=64. global_load_lds staging with
// XOR-swizzled global source (linear LDS dest) + swizzled reads.
// EPI: 0 none; 1 relu(v*sc[n]+bi[n]); 2 v*cscale; 3 v+bi[n]; 4 v+bi[m]
template<int EPI, typename TC>
__global__ __launch_bounds__(256) void gemm_bf16(
    const unsigned short* __restrict__ A, long sA, int lda,
    const unsigned short* __restrict__ B, long sB, int ldb,
    TC* __restrict__ C, long sC, int ldc,
    int M, int N, int K,
    const float* __restrict__ sc, const float* __restrict__ bi, float cscale)
{
  __shared__ short As[128 * 64];
  __shared__ short Bs[128 * 64];
  const int tid = threadIdx.x;
  const int lane = tid & 63, wid = tid >> 6;
  const int wm = wid >> 1, wn = wid & 1;
  const int l15 = lane & 15, l4 = lane >> 4, l7 = lane & 7;
  const int bm = blockIdx.y * 128, bn = blockIdx.x * 128;
  const int srow = lane >> 3;           // 0..7 within staged 8-row group
  A += (long)blockIdx.z * sA; B += (long)blockIdx.z * sB; C += (long)blockIdx.z * sC;
  f32x4 acc[4][4] = {};
  for (int k0 = 0; k0 < K; k0 += 64) {
#pragma unroll
    for (int i = 0; i < 4; i++) {
      int row = (wid * 4 + i) * 8 + srow;             // tile row 0..127
      int gcol = (l7 ^ (row & 7)) * 8;                // swizzled k-chunk
      GLDS16(A + (long)(bm + row) * lda + k0 + gcol, &As[(wid * 4 + i) * 512]);
      GLDS16(B + (long)(bn + row) * ldb + k0 + gcol, &Bs[(wid * 4 + i) * 512]);
    }
    __syncthreads();
#pragma unroll
    for (int ks = 0; ks < 2; ks++) {
      bf16x8 af[4], bfr[4];
#pragma unroll
      for (int t = 0; t < 4; t++) {
        int ra = wm * 64 + t * 16 + l15;
        int rb = wn * 64 + t * 16 + l15;
        int ch = (l4 + 4 * ks) ^ (l15 & 7);
        af[t]  = *(const bf16x8*)&As[ra * 64 + ch * 8];
        bfr[t] = *(const bf16x8*)&Bs[rb * 64 + ch * 8];
      }
#pragma unroll
      for (int i = 0; i < 4; i++)
#pragma unroll
        for (int j2 = 0; j2 < 4; j2++)
          acc[i][j2] = __builtin_amdgcn_mfma_f32_16x16x32_bf16(af[i], bfr[j2], acc[i][j2], 0, 0, 0);
    }
    __syncthreads();
  }
#pragma unroll
  for (int i = 0; i < 4; i++) {
#pragma unroll
    for (int j2 = 0; j2 < 4; j2++) {
      int n = bn + wn * 64 + j2 * 16 + l15;
#pragma unroll
      for (int j = 0; j < 4; j++) {
        int m = bm + wm * 64 + i * 16 + l4 * 4 + j;
        float v = acc[i][j2][j];
        if (EPI == 1) v = fmaxf(fmaf(v, sc[n], bi[n]), 0.f);
        if (EPI == 2) v *= cscale;
        if (EPI == 3) v += bi[n];
        if (EPI == 4) v += bi[m];
        st(&C[(long)m * ldc + n], v);
      }
    }
  }
}

// ---------- flash attention, 32x32x16 MFMA, operand-swapped, in-register softmax ----
// 256 threads = 4 waves, 32 q-rows/wave -> 128 q-rows/block.
// qk: [B,S,1024] bf16 (cols 0-511 = q prescaled, 512-1023 = k); vT: [B,512,S] bf16.
// No P LDS roundtrip: cvt_pk_bf16 + permlane32_swap builds the PV B-fragment in-register.
__global__ __launch_bounds__(256) void attn_flash(
    const unsigned short* __restrict__ qk, const unsigned short* __restrict__ vT,
    float* __restrict__ out, int S)
{
  __shared__ short Ks[2][64 * 128];   // [kv][d], XOR-swizzled 16B chunks (16KB each)
  __shared__ short Vs[2][128 * 64];   // [d][kv], XOR-swizzled (16KB each)
  const int tid = threadIdx.x, lane = tid & 63, wid = tid >> 6;  // 4 waves
  const int h = blockIdx.y, b = blockIdx.z;
  const int l31 = lane & 31, hi = lane >> 5, l7 = l31 & 7;
  const long qkb = (long)b * S * 1024;
  const long vbb = (long)b * 512 * S;
  const long obase = (long)b * S * 512;
  const int qr0 = blockIdx.x * 128 + wid * 32;
  // Q as B-operand: col q = qr0+l31, k-slot c: d = c*16 + hi*8 + j
  bf16x8 qf[8];
#pragma unroll
  for (int c = 0; c < 8; c++)
    qf[c] = *(const bf16x8*)(qk + qkb + (long)(qr0 + l31) * 1024 + h * 128 + c * 16 + hi * 8);
  f32x16 O[4] = {};                    // O[dt]: d = dt*32+dloc, q = l31
  float m_run = -1e30f, l_run = 0.f;
  const int NT = S >> 6;
  auto stage = [&](int bi, int kt) {
#pragma unroll
    for (int i = 0; i < 4; i++) {
      int krow = wid * 16 + i * 4 + (lane >> 4);       // 4 rows / wave-issue
      GLDS16(qk + qkb + (long)(kt * 64 + krow) * 1024 + 512 + h * 128 + (((lane & 15) ^ (krow & 7)) << 3),
             &Ks[bi][(wid * 16 + i * 4) * 128]);
      int vrow = wid * 32 + i * 8 + (lane >> 3);       // 8 rows / wave-issue
      GLDS16(vT + vbb + (long)(h * 128 + vrow) * S + kt * 64 + (((lane & 7) ^ (vrow & 7)) << 3),
             &Vs[bi][(wid * 32 + i * 8) * 64]);
    }
  };
  stage(0, 0);
  int cur = 0;
  for (int kt = 0; kt < NT; kt++) {
    __syncthreads();                            // drains prefetch; tile `cur` ready
    if (kt + 1 < NT) stage(cur ^ 1, kt + 1);    // prefetch overlaps compute below
    // QK^T (swapped): D[kv][q]; s0 = kv 0-31 tile, s1 = kv 32-63.
    f32x16 s0 = {}, s1 = {};
    __builtin_amdgcn_s_setprio(1);
#pragma unroll
    for (int c = 0; c < 8; c++) {
      int sl = ((c * 2 + hi) ^ l7) << 3;        // swizzled 16B slot (in shorts)
      bf16x8 k0 = *(const bf16x8*)&Ks[cur][l31 * 128 + sl];
      bf16x8 k1 = *(const bf16x8*)&Ks[cur][(32 + l31) * 128 + sl];
      s0 = __builtin_amdgcn_mfma_f32_32x32x16_bf16(k0, qf[c], s0, 0, 0, 0);
      s1 = __builtin_amdgcn_mfma_f32_32x32x16_bf16(k1, qf[c], s1, 0, 0, 0);
    }
    __builtin_amdgcn_s_setprio(0);
    // lane holds 32 scores of q-row (qr0+l31); partner lane (^32) holds the other 32
    float pmax = -1e30f;
#pragma unroll
    for (int r = 0; r < 16; r++) { pmax = fmaxf(pmax, s0[r]); pmax = fmaxf(pmax, s1[r]); }
    pmax = fmaxf(pmax, __shfl_xor(pmax, 32, 64));
    if (!__all(pmax - m_run <= 8.f)) {          // defer-max (T13)
      float m_new = fmaxf(m_run, pmax);
      float corr = __expf(m_run - m_new);
      l_run *= corr; m_run = m_new;
#pragma unroll
      for (int dt = 0; dt < 4; dt++)
#pragma unroll
        for (int r = 0; r < 16; r++) O[dt][r] *= corr;
    }
    // exp + in-register P fragment build (T12): per kvc, quad-a/quad-b cvt_pk then
    // permlane32_swap pairs (w0,w2) and (w1,w3) -> B-operand frag k = hi*8+j.
    float ts = 0.f;
    bf16x8 pf[4];
#pragma unroll
    for (int kvc = 0; kvc < 4; kvc++) {
      float e0, e1, e2, e3, e4, e5, e6, e7;
      if (kvc == 0) {
        e0=__expf(s0[0]-m_run);  e1=__expf(s0[1]-m_run);  e2=__expf(s0[2]-m_run);  e3=__expf(s0[3]-m_run);
        e4=__expf(s0[4]-m_run);  e5=__expf(s0[5]-m_run);  e6=__expf(s0[6]-m_run);  e7=__expf(s0[7]-m_run);
      } else if (kvc == 1) {
        e0=__expf(s0[8]-m_run);  e1=__expf(s0[9]-m_run);  e2=__expf(s0[10]-m_run); e3=__expf(s0[11]-m_run);
        e4=__expf(s0[12]-m_run); e5=__expf(s0[13]-m_run); e6=__expf(s0[14]-m_run); e7=__expf(s0[15]-m_run);
      } else if (kvc == 2) {
        e0=__expf(s1[0]-m_run);  e1=__expf(s1[1]-m_run);  e2=__expf(s1[2]-m_run);  e3=__expf(s1[3]-m_run);
        e4=__expf(s1[4]-m_run);  e5=__expf(s1[5]-m_run);  e6=__expf(s1[6]-m_run);  e7=__expf(s1[7]-m_run);
      } else {
        e0=__expf(s1[8]-m_run);  e1=__expf(s1[9]-m_run);  e2=__expf(s1[10]-m_run); e3=__expf(s1[11]-m_run);
        e4=__expf(s1[12]-m_run); e5=__expf(s1[13]-m_run); e6=__expf(s1[14]-m_run); e7=__expf(s1[15]-m_run);
      }
      ts += e0 + e1 + e2 + e3 + e4 + e5 + e6 + e7;
      unsigned w0, w1, w2, w3;
      asm("v_cvt_pk_bf16_f32 %0, %1, %2" : "=v"(w0) : "v"(e0), "v"(e1));
      asm("v_cvt_pk_bf16_f32 %0, %1, %2" : "=v"(w1) : "v"(e2), "v"(e3));
      asm("v_cvt_pk_bf16_f32 %0, %1, %2" : "=v"(w2) : "v"(e4), "v"(e5));
      asm("v_cvt_pk_bf16_f32 %0, %1, %2" : "=v"(w3) : "v"(e6), "v"(e7));
      asm("v_permlane32_swap_b32 %0, %1" : "+v"(w0), "+v"(w2));
      asm("v_permlane32_swap_b32 %0, %1" : "+v"(w1), "+v"(w3));
      union { unsigned u[4]; bf16x8 v; } pk;
      pk.u[0] = w0; pk.u[1] = w1; pk.u[2] = w2; pk.u[3] = w3;
      pf[kvc] = pk.v;
    }
    ts += __shfl_xor(ts, 32, 64);
    l_run += ts;
    // PV (swapped): O[d][q] += V^T[d][kv] * P[kv][q]
    __builtin_amdgcn_s_setprio(1);
#pragma unroll
    for (int kvc = 0; kvc < 4; kvc++) {
#pragma unroll
      for (int dt = 0; dt < 4; dt++) {
        bf16x8 vf = *(const bf16x8*)&Vs[cur][(dt * 32 + l31) * 64 + (((kvc * 2 + hi) ^ l7) << 3)];
        O[dt] = __builtin_amdgcn_mfma_f32_32x32x16_bf16(vf, pf[kvc], O[dt], 0, 0, 0);
      }
    }
    __builtin_amdgcn_s_setprio(0);
    cur ^= 1;
  }
  float inv = 1.f / l_run;
  float* op = out + obase + (long)(qr0 + l31) * 512 + h * 128;
#pragma unroll
  for (int dt = 0; dt < 4; dt++) {
#pragma unroll
    for (int q4 = 0; q4 < 4; q4++) {
      f32x4 ov;
      ov[0] = O[dt][q4 * 4 + 0] * inv;
      ov[1] = O[dt][q4 * 4 + 1] * inv;
      ov[2] = O[dt][q4 * 4 + 2] * inv;
      ov[3] = O[dt][q4 * 4 + 3] * inv;
      *(f32x4*)&op[dt * 32 + q4 * 8 + hi * 4] = ov;   // d = dt*32 + q4*8 + hi*4 + j
    }
  }
}

// ---------- residual add + LayerNorm over E=512 ----------
template<typename TD>
__global__ __launch_bounds__(256) void add_ln(
    const float* __restrict__ att, const unsigned short* __restrict__ resid,
    const float* __restrict__ g, const float* __restrict__ bt,
    TD* __restrict__ dst, long db, int S)
{
  __shared__ float red[4];
  int b = blockIdx.y, s = blockIdx.x, tid = threadIdx.x;
  const float* ap = att + ((long)b * S + s) * 512;
  const unsigned short* rp = resid + ((long)b * S + s) * 512;
  float y0 = ap[tid] + b2f(rp[tid]);
  float y1 = ap[tid + 256] + b2f(rp[tid + 256]);
  float mu = bred_sum(y0 + y1, red) * (1.f / 512.f);
  float d0 = y0 - mu, d1 = y1 - mu;
  float var = bred_sum(d0 * d0 + d1 * d1, red) * (1.f / 512.f);
  float rsv = rsqrtf(var + LN_EPS);
  TD* dp = dst + (long)b * db + (long)s * 512;
  st(&dp[tid], d0 * rsv * g[tid] + bt[tid]);
  st(&dp[tid + 256], d1 * rsv * g[tid + 256] + bt[tid + 256]);
}

extern "C" void kernel_launch(void* const* d_in, const int* in_sizes, int n_in,
                              void* d_out, int out_size, void* d_ws, size_t ws_size,
                              hipStream_t stream) {
  (void)in_sizes; (void)n_in; (void)out_size; (void)ws_size;
  const float* img = (const float*)d_in[0];
  const float* pts = (const float*)d_in[1];
  const float* w1  = (const float*)d_in[2];
  const float* b1  = (const float*)d_in[3];
  const float* g1  = (const float*)d_in[4];
  const float* be1 = (const float*)d_in[5];
  const float* m1  = (const float*)d_in[6];
  const float* v1  = (const float*)d_in[7];
  const float* w2  = (const float*)d_in[8];
  const float* b2  = (const float*)d_in[9];
  const float* g2  = (const float*)d_in[10];
  const float* be2 = (const float*)d_in[11];
  const float* m2  = (const float*)d_in[12];
  const float* v2  = (const float*)d_in[13];
  const float* qw  = (const float*)d_in[14];
  const float* qb  = (const float*)d_in[15];
  const float* kw  = (const float*)d_in[16];
  const float* kb  = (const float*)d_in[17];
  const float* vw  = (const float*)d_in[18];
  const float* vb  = (const float*)d_in[19];
  const float* lng = (const float*)d_in[20];
  const float* lnb = (const float*)d_in[21];
  float* out = (float*)d_out;
  float* ws  = (float*)d_ws;
  typedef unsigned short u16;

  // ---- arena (f32-slot offsets), total ~157.8 MB ----
  u16*   xTu   = (u16*)ws;                       // [4][3072][512] bf16
  float* phi   = ws;                             // [4][2048][1024] f32
  u16*   y1u   = (u16*)(ws + 8388608);           // [4][3072][1024] bf16
  float* phiT  = ws + 8388608;                   // [4][1024][2048] f32
  u16*   featu = (u16*)(ws + 16777216);          // [4][3072][512] bf16
  u16*   featTu= (u16*)(ws + 19922944);          // [4][512][3072] bf16
  u16*   smI   = (u16*)(ws + 23068672);          // phi_i softmax  [4][2048][1024] bf16
  u16*   smPT  = (u16*)(ws + 27262976);          // phi_p^T softmax [4][1024][2048] bf16
  u16*   Xi    = (u16*)(ws + 31457280);          // [4][1024][512] bf16
  u16*   Xp    = (u16*)(ws + 32505856);          // [4][2048][512] bf16
  u16*   jointu= (u16*)(ws + 34603008);          // [4][3072][512] bf16
  u16*   w1b   = (u16*)(ws + 37748736);
  u16*   w2b   = (u16*)(ws + 38010880);
  u16*   qkwb  = (u16*)(ws + 38273024);          // [3][1024][512] bf16 (q||k, q prescaled)
  u16*   vwb   = (u16*)(ws + 39059456);
  float* s1f   = ws + 39452672;
  float* f1f   = s1f + 1024;
  float* s2f   = f1f + 1024;
  float* f2f   = s2f + 512;
  float* qkbf  = ws + 39455744;                  // [3][1024] f32 bias (q prescaled)
  // attention scratch (A0/B0 regions after phi/phiT are dead)
  u16*   qkbu  = (u16*)ws;                       // [4][S<=3072][1024] bf16
  u16*   vTu   = (u16*)(ws + 6291456);           // [4][512][S] bf16
  float* attf  = ws + 9437184;                   // [4][S][512] f32

  dim3 blk(256);
  fold_bn<<<dim3(4), blk, 0, stream>>>(b1, g1, be1, m1, v1, b2, g2, be2, m2, v2, s1f, f1f, s2f, f2f);
  cvt_bf16<<<dim3(2048), blk, 0, stream>>>(w1, w1b, 524288);
  cvt_bf16<<<dim3(2048), blk, 0, stream>>>(w2, w2b, 524288);
  cvt_bf16<<<dim3(3072), blk, 0, stream>>>(vw, vwb, 786432);
  prep_qk<<<dim3(6144), blk, 0, stream>>>(qw, qb, kw, kb, qkwb, qkbf);

  // xT: [pos, 512] bf16 (points rows 0..2047, img rows 2048..3071)
  transpose_t<float, u16><<<dim3(64, 16, 4), blk, 0, stream>>>(pts, xTu, 512, 2048, 1048576L, 1572864L);
  transpose_t<float, u16><<<dim3(32, 16, 4), blk, 0, stream>>>(img, xTu + 1048576, 512, 1024, 524288L, 1572864L);

  // MLP1: y1[pos,1024] = relu(bn1(xT @ w1^T))
  gemm_bf16<1, u16><<<dim3(8, 24, 4), blk, 0, stream>>>(xTu, 1572864L, 512, w1b, 0L, 512,
      y1u, 3145728L, 1024, 3072, 1024, 512, s1f, f1f, 0.f);
  // MLP2: feat[pos,512]
  gemm_bf16<1, u16><<<dim3(4, 24, 4), blk, 0, stream>>>(y1u, 3145728L, 1024, w2b, 0L, 1024,
      featu, 1572864L, 512, 3072, 512, 1024, s2f, f2f, 0.f);
  // featT [512, 3072]
  transpose_t<u16, u16><<<dim3(16, 96, 4), blk, 0, stream>>>(featu, featTu, 3072, 512, 1572864L, 1572864L);
  // phi[p,i] f32
  gemm_bf16<2, float><<<dim3(8, 16, 4), blk, 0, stream>>>(featu, 1572864L, 512, featu + 1048576, 1572864L, 512,
      phi, 2097152L, 1024, 2048, 1024, 512, nullptr, nullptr, 0.044194173824159216f);
  transpose_t<float, float><<<dim3(32, 64, 4), blk, 0, stream>>>(phi, phiT, 2048, 1024, 2097152L, 2097152L);
  softmax_k<4><<<dim3(2048, 4), blk, 0, stream>>>(phi, smI, 2097152L);    // softmax over i
  softmax_k<8><<<dim3(1024, 4), blk, 0, stream>>>(phiT, smPT, 2097152L);  // softmax over p
  // Xi[i,c] = phi_p^T @ featP^T ; Xp[p,c] = phi_i @ featI^T
  gemm_bf16<0, u16><<<dim3(4, 8, 4), blk, 0, stream>>>(smPT, 2097152L, 2048, featTu, 1572864L, 3072,
      Xi, 524288L, 512, 1024, 512, 2048, nullptr, nullptr, 0.f);
  gemm_bf16<0, u16><<<dim3(4, 16, 4), blk, 0, stream>>>(smI, 2097152L, 1024, featTu + 2048, 1572864L, 3072,
      Xp, 1048576L, 512, 2048, 512, 1024, nullptr, nullptr, 0.f);

  struct AttCfg { const u16* X; int S; int j; };
  AttCfg cfgs[3] = { {Xi, 1024, 0}, {Xp, 2048, 1}, {jointu, 3072, 2} };
  for (int a = 0; a < 3; a++) {
    const u16* X = cfgs[a].X; int S = cfgs[a].S; int j = cfgs[a].j;
    long xs = (long)S * 512;
    // fused QK projection: [S,1024] (q cols 0-511 prescaled, k cols 512-1023)
    gemm_bf16<3, u16><<<dim3(8, S / 128, 4), blk, 0, stream>>>(X, xs, 512, qkwb + j * 524288, 0L, 512,
        qkbu, (long)S * 1024, 1024, S, 1024, 512, nullptr, qkbf + j * 1024, 0.f);
    gemm_bf16<4, u16><<<dim3(S / 128, 4, 4), blk, 0, stream>>>(vwb + j * 262144, 0L, 512, X, xs, 512,
        vTu, xs, S, 512, S, 512, nullptr, vb + j * 512, 0.f);
    attn_flash<<<dim3(S / 128, 4, 4), blk, 0, stream>>>(qkbu, vTu, attf, S);
    if (a == 0)
      add_ln<u16><<<dim3(S, 4), blk, 0, stream>>>(attf, X, lng + j * 512, lnb + j * 512,
          jointu + 1048576, 1572864L, S);
    else if (a == 1)
      add_ln<u16><<<dim3(S, 4), blk, 0, stream>>>(attf, X, lng + j * 512, lnb + j * 512,
          jointu, 1572864L, S);
    else
      add_ln<float><<<dim3(S, 4), blk, 0, stream>>>(attf, X, lng + j * 512, lnb + j * 512,
          out, 1572864L, S);
  }
}